// Round 5
// baseline (1316.378 us; speedup 1.0000x reference)
//
#include <hip/hip_runtime.h>
#include <hip/hip_bf16.h>

// ===========================================================================
// EEGRCformer forward on MI355X. ALL tensors float32.
// R5: feat_kernel v5 — R4 register-bin structure + coalesced LDS staging of x
// (R4's global x reads caused 1.75GB/dispatch fetch). Basis stays in global
// with wave-uniform (scalarized s_load) addresses. 7 signals/block,
// xs stride 2004 (16B-aligned rows), 2 blocks/CU.
// ws layout (floats): feats[128*62*504] | pf[128*62*128] (aliased by Dpart
// 256*3844 before proj) | gsums[15] | gcnt[5] | assign[62 ints] | basis[45*504]
// ===========================================================================

typedef unsigned int u32;

#define N_SIG   7936          // 128*62
#define FDIM    504           // 36*14
#define DM      128
#define XSTR    2004          // LDS row stride for staged x (16B aligned)

__device__ __constant__ int band_of_c[46] = {
    -1, 0,0,0, 1,1,1,1, 2,2,2,2, 3,3,3,3, 4,4,4,4,
    5,5,5,5,5,5,5,5,5,5,
    6,6,6,6,6,6,6,6,6,6,6,6,6,6,6, -1};
__device__ __constant__ float bandcnt_c[7] = {3.f,4.f,4.f,4.f,4.f,10.f,15.f};

// block reduce of (a,b) over 128 threads (2 waves); scr must be >=4 floats
static __device__ __forceinline__ void bred2(float& a, float& b, volatile float* scr, int tid){
    #pragma unroll
    for (int off = 32; off > 0; off >>= 1){
        a += __shfl_down(a, off, 64);
        b += __shfl_down(b, off, 64);
    }
    if ((tid & 63) == 0){ scr[tid>>6] = a; scr[2 + (tid>>6)] = b; }
    __syncthreads();
    a = scr[0] + scr[1];
    b = scr[2] + scr[3];
    __syncthreads();
}

// ---------------------------------------------------------------------------
// Kernel 0: precompute Hann-folded DFT basis -> global.
// Row g1 (0..44) = bin g1+1: cos at [g1*504 + 0..249], sin at [+252..501].
// ---------------------------------------------------------------------------
__global__ __launch_bounds__(256) void basis_kernel(float* __restrict__ basis)
{
    int idx = blockIdx.x*256 + threadIdx.x;      // over 45*252
    if (idx >= 45*252) return;
    int g1 = idx / 252;
    int n  = idx - g1*252;
    float vc = 0.f, vs = 0.f;
    if (g1 < 44 && n < 250){
        const float TPO = 0.025132741228718345f; // 2*pi/250
        int k = g1 + 1;
        int m = (k*n) % 250;                     // exact reduction
        float th = (float)m * TPO;
        float sn, csn; sincosf(th, &sn, &csn);
        float hw = 0.5f*(1.f - cosf((float)n * TPO));
        vc = hw*csn; vs = hw*sn;
    }
    basis[(size_t)g1*504 + n]       = vc;
    basis[(size_t)g1*504 + 252 + n] = vs;
}

// ---------------------------------------------------------------------------
// Kernel A: windowed DFT -> band PSD + DE -> per-signal z-norm -> feats
// 1134 blocks x 256 threads; 7 signals per block; thread=(s,win), all 11
// bins of each cc in registers; x staged in LDS (coalesced), basis scalar.
// ---------------------------------------------------------------------------
__global__ __launch_bounds__(256, 2) void feat_kernel(
        const float* __restrict__ x, const float* __restrict__ basis,
        float* __restrict__ feats,
        float* __restrict__ gsums, float* __restrict__ gcnt)
{
    __shared__ float xs[7*XSTR];     // staged signal rows
    __shared__ float psum[7*252];    // band power sums

    const int tid  = threadIdx.x;
    const int sig0 = blockIdx.x * 7;

    if (blockIdx.x == 0 && tid < 20){
        if (tid < 15) gsums[tid] = 0.f; else gcnt[tid-15] = 0.f;
    }

    // coalesced staging: 7 rows x 500 float4
    for (int idx = tid; idx < 7*500; idx += 256){
        int r = idx / 500, c = idx - r*500;
        int sig = sig0 + r;
        float4 v = make_float4(0.f,0.f,0.f,0.f);
        if (sig < N_SIG) v = *(const float4*)(x + (size_t)sig*2000 + 4*c);
        *(float4*)(xs + r*XSTR + 4*c) = v;
    }
    for (int i = tid; i < 7*252; i += 256) psum[i] = 0.f;
    __syncthreads();

    if (tid < 252){
        const int s   = tid / 36;
        const int win = tid - s*36;
        const float2* xp = (const float2*)(xs + s*XSTR + 50*win);

        for (int cc = 0; cc < 4; ++cc){
            const float* bp = basis + (size_t)(cc*11)*504;

            float ar[11], ai[11];
            #pragma unroll
            for (int k = 0; k < 11; ++k){ ar[k] = 0.f; ai[k] = 0.f; }

            #pragma unroll 2
            for (int q = 0; q < 62; ++q){
                float2 u0 = xp[2*q], u1 = xp[2*q + 1];
                float x0 = u0.x, x1 = u0.y, x2 = u1.x, x3 = u1.y;
                #pragma unroll
                for (int k = 0; k < 11; ++k){
                    float4 c  = *(const float4*)(bp + k*504 + 4*q);
                    float4 sn = *(const float4*)(bp + k*504 + 252 + 4*q);
                    float r = ar[k], im = ai[k];
                    r  = fmaf(x0, c.x, r);  r  = fmaf(x1, c.y, r);
                    r  = fmaf(x2, c.z, r);  r  = fmaf(x3, c.w, r);
                    im = fmaf(x0, sn.x, im); im = fmaf(x1, sn.y, im);
                    im = fmaf(x2, sn.z, im); im = fmaf(x3, sn.w, im);
                    ar[k] = r; ai[k] = im;
                }
            }
            // tail n = 248, 249
            {
                float2 xt = xp[124];
                #pragma unroll
                for (int k = 0; k < 11; ++k){
                    float c0 = bp[k*504 + 248],       c1 = bp[k*504 + 249];
                    float s0 = bp[k*504 + 252 + 248], s1 = bp[k*504 + 252 + 249];
                    ar[k] = fmaf(xt.x, c0, ar[k]); ar[k] = fmaf(xt.y, c1, ar[k]);
                    ai[k] = fmaf(xt.x, s0, ai[k]); ai[k] = fmaf(xt.y, s1, ai[k]);
                }
            }
            // band-grouped accumulate into psum
            {
                const int kA0 = 1 + cc*11;
                float bsum = 0.f;
                int cur = band_of_c[kA0];
                #pragma unroll
                for (int k = 0; k < 11; ++k){
                    int bnd = band_of_c[kA0 + k];
                    float p = fmaf(ar[k], ar[k], ai[k]*ai[k]) * (1.0f/250.0f);
                    if (bnd != cur){
                        atomicAdd(&psum[s*252 + win*7 + cur], bsum);
                        bsum = 0.f; cur = bnd;
                    }
                    bsum += p;
                }
                atomicAdd(&psum[s*252 + win*7 + cur], bsum);
            }
        }
    }
    __syncthreads();

    // per-signal normalization: one wave per signal, 2 rounds (7 signals)
    const int wv = tid >> 6, lane = tid & 63;
    for (int r = 0; r < 2; ++r){
        int sl = wv + r*4;
        if (sl >= 7) continue;
        float s1p=0,s2p=0,s1d=0,s2d=0;
        for (int e = lane; e < 252; e += 64){
            int bi = e % 7;
            float psd = psum[sl*252 + e] / bandcnt_c[bi];
            float de  = 0.5f * logf(17.079468445347134f*psd + 1e-9f);
            s1p += psd; s2p += psd*psd; s1d += de; s2d += de*de;
        }
        #pragma unroll
        for (int off = 32; off > 0; off >>= 1){
            s1p += __shfl_down(s1p, off, 64); s2p += __shfl_down(s2p, off, 64);
            s1d += __shfl_down(s1d, off, 64); s2d += __shfl_down(s2d, off, 64);
        }
        s1p = __shfl(s1p, 0, 64); s2p = __shfl(s2p, 0, 64);
        s1d = __shfl(s1d, 0, 64); s2d = __shfl(s2d, 0, 64);
        float mp = s1p / 252.f;
        float vp = fmaxf((s2p - 252.f*mp*mp) / 251.f, 0.f);
        float sp = sqrtf(vp) + 1e-9f;
        float md = s1d / 252.f;
        float vd = fmaxf((s2d - 252.f*md*md) / 251.f, 0.f);
        float sd = sqrtf(vd) + 1e-9f;

        int sig = sig0 + sl;
        if (sig < N_SIG){
            float* ob = feats + (size_t)sig * FDIM;
            for (int e = lane; e < 252; e += 64){
                int w = e / 7, bi = e - w*7;
                float psd = psum[sl*252 + e] / bandcnt_c[bi];
                float de  = 0.5f * logf(17.079468445347134f*psd + 1e-9f);
                ob[w*14 + bi]     = (psd - mp) / sp;
                ob[w*14 + 7 + bi] = (de  - md) / sd;
            }
        }
    }
}

// ---------------------------------------------------------------------------
// Kernel B1: partial squared distances. 256 blocks = (batch, half of K).
// Writes Dpart[(b*2+half)*3844 + e] (fp32, no init needed).
// ---------------------------------------------------------------------------
__global__ __launch_bounds__(256) void dist2_kernel(
        const float* __restrict__ feats, float* __restrict__ Dpart)
{
    __shared__ float Fc[62*254];     // stride 254 floats (127 odd -> no conflicts)
    const int tid  = threadIdx.x;
    const int b    = blockIdx.x >> 1;
    const int half = blockIdx.x & 1;

    for (int i = tid; i < 62*126; i += 256){
        int r = i / 126, c2 = i - r*126;
        *(float2*)&Fc[r*254 + 2*c2] =
            *(const float2*)&feats[((size_t)b*62 + r)*FDIM + half*252 + 2*c2];
    }
    __syncthreads();

    for (int e = tid; e < 3844; e += 256){
        int i = e / 62, j = e - i*62;
        const float2* ri = (const float2*)(Fc + i*254);
        const float2* rj = (const float2*)(Fc + j*254);
        float acc = 0.f;
        for (int t = 0; t < 126; ++t){
            float2 a = ri[t], c = rj[t];
            float d0 = a.x - c.x, d1 = a.y - c.y;
            acc = fmaf(d0, d0, acc); acc = fmaf(d1, d1, acc);
        }
        Dpart[(size_t)blockIdx.x*3844 + e] = acc;
    }
}

// ---------------------------------------------------------------------------
// Kernel B2: Dm = sqrt(sum halves) -> FPS(5) -> temp assign -> atomic pos
// sums/counts. 128 blocks x 256 threads.
// ---------------------------------------------------------------------------
__global__ __launch_bounds__(256) void fps_kernel(
        const float* __restrict__ Dpart, const float* __restrict__ pos_emb,
        float* __restrict__ gsums, float* __restrict__ gcnt)
{
    __shared__ float Dm[62*62];
    __shared__ float mdv[62];
    __shared__ float rsv[62];
    __shared__ int   seli[5];
    __shared__ float ccen[5][3];

    const int tid = threadIdx.x;
    const int b   = blockIdx.x;

    for (int e = tid; e < 3844; e += 256)
        Dm[e] = sqrtf(Dpart[(size_t)(b*2)*3844 + e] + Dpart[(size_t)(b*2+1)*3844 + e]);
    __syncthreads();

    if (tid < 62){ float s = 0.f; for (int j = 0; j < 62; ++j) s += Dm[tid*62 + j]; rsv[tid] = s; }
    __syncthreads();
    if (tid == 0){
        int bi = 0; float bv = rsv[0];
        for (int i = 1; i < 62; ++i) if (rsv[i] > bv){ bv = rsv[i]; bi = i; }
        seli[0] = bi;
    }
    __syncthreads();
    if (tid < 62) mdv[tid] = Dm[seli[0]*62 + tid];
    __syncthreads();
    for (int it = 1; it < 5; ++it){
        if (tid == 0){
            int bi = 0; float bv = mdv[0];
            for (int i = 1; i < 62; ++i) if (mdv[i] > bv){ bv = mdv[i]; bi = i; }
            seli[it] = bi;
        }
        __syncthreads();
        if (tid < 62) mdv[tid] = fminf(mdv[tid], Dm[seli[it]*62 + tid]);
        __syncthreads();
    }
    if (tid < 5){
        int c0 = seli[tid];
        #pragma unroll
        for (int j = 0; j < 3; ++j) ccen[tid][j] = pos_emb[((size_t)b*62 + c0)*3 + j];
    }
    __syncthreads();
    if (tid < 62){
        float px = pos_emb[((size_t)b*62 + tid)*3 + 0];
        float py = pos_emb[((size_t)b*62 + tid)*3 + 1];
        float pz = pos_emb[((size_t)b*62 + tid)*3 + 2];
        int best = 0; float bd = 3.4e38f;
        #pragma unroll
        for (int t = 0; t < 5; ++t){
            float dx = px - ccen[t][0], dy = py - ccen[t][1], dz = pz - ccen[t][2];
            float d2 = dx*dx + dy*dy + dz*dz;
            if (d2 < bd){ bd = d2; best = t; }
        }
        atomicAdd(&gsums[best*3 + 0], px);
        atomicAdd(&gsums[best*3 + 1], py);
        atomicAdd(&gsums[best*3 + 2], pz);
        atomicAdd(&gcnt[best], 1.f);
    }
}

// ---------------------------------------------------------------------------
// Kernel C: pos FPS centers, center update, stable order (parallel) + greedy
// assignment (serial tail). 1 block x 64 threads.
// ---------------------------------------------------------------------------
__global__ __launch_bounds__(64) void finalize_kernel(
        const float* __restrict__ pos_emb, const float* __restrict__ gsums,
        const float* __restrict__ gcnt, int* __restrict__ assign_out)
{
    __shared__ float P[62*3];
    __shared__ float Dp[62*62];
    __shared__ float rsv[62];
    __shared__ float mdv[62];
    __shared__ int   seli[5];
    __shared__ float cenS[5][3];
    __shared__ int   ordS[62][5];
    const int tid = threadIdx.x;

    if (tid < 62){
        #pragma unroll
        for (int j = 0; j < 3; ++j) P[tid*3 + j] = pos_emb[(size_t)tid*3 + j];
    }
    __syncthreads();
    if (tid < 62){
        float xi = P[tid*3], yi = P[tid*3+1], zi = P[tid*3+2];
        float s = 0.f;
        for (int j = 0; j < 62; ++j){
            float dx = xi - P[j*3], dy = yi - P[j*3+1], dz = zi - P[j*3+2];
            float d = sqrtf(dx*dx + dy*dy + dz*dz);
            Dp[tid*62 + j] = d; s += d;
        }
        rsv[tid] = s;
    }
    __syncthreads();
    if (tid == 0){
        int bi = 0; float bv = rsv[0];
        for (int i = 1; i < 62; ++i) if (rsv[i] > bv){ bv = rsv[i]; bi = i; }
        seli[0] = bi;
        for (int i = 0; i < 62; ++i) mdv[i] = Dp[bi*62 + i];
        for (int it = 1; it < 5; ++it){
            int fi = 0; float fv = mdv[0];
            for (int i = 1; i < 62; ++i) if (mdv[i] > fv){ fv = mdv[i]; fi = i; }
            seli[it] = fi;
            for (int i = 0; i < 62; ++i) mdv[i] = fminf(mdv[i], Dp[fi*62 + i]);
        }
        float cen[5][3], avg[5][3];
        for (int t = 0; t < 5; ++t)
            for (int j = 0; j < 3; ++j) cen[t][j] = P[seli[t]*3 + j];
        for (int t = 0; t < 5; ++t){
            float c = gcnt[t];
            for (int j = 0; j < 3; ++j)
                avg[t][j] = (c > 0.f) ? gsums[t*3 + j] / fmaxf(c, 1.f) : 0.f;
        }
        for (int i = 0; i < 5; ++i){
            int m = 0; float bv2 = 3.4e38f;
            for (int j = 0; j < 5; ++j){
                float dx = cen[i][0]-avg[j][0], dy = cen[i][1]-avg[j][1], dz = cen[i][2]-avg[j][2];
                float d2 = dx*dx + dy*dy + dz*dz;
                if (d2 < bv2){ bv2 = d2; m = j; }
            }
            for (int j = 0; j < 3; ++j) cenS[i][j] = 0.8f*cen[i][j] + 0.2f*avg[m][j];
        }
    }
    __syncthreads();
    if (tid < 62){
        float dd[5];
        #pragma unroll
        for (int t = 0; t < 5; ++t){
            float dx = P[tid*3]-cenS[t][0], dy = P[tid*3+1]-cenS[t][1], dz = P[tid*3+2]-cenS[t][2];
            dd[t] = sqrtf(dx*dx + dy*dy + dz*dz);
        }
        bool tk[5] = {false,false,false,false,false};
        #pragma unroll
        for (int s = 0; s < 5; ++s){
            int best = -1;
            #pragma unroll
            for (int t = 0; t < 5; ++t)
                if (!tk[t] && (best < 0 || dd[t] < dd[best])) best = t;
            tk[best] = true; ordS[tid][s] = best;
        }
    }
    __syncthreads();
    if (tid == 0){
        const int sizesA[5] = {13,13,12,12,12};
        int counts[5] = {0,0,0,0,0};
        for (int i = 0; i < 62; ++i){
            int cl = ordS[i][0];
            #pragma unroll
            for (int s = 0; s < 5; ++s){
                int t = ordS[i][s];
                if (counts[t] < sizesA[t]){ cl = t; break; }
            }
            counts[cl]++;
            assign_out[i] = cl;
        }
    }
}

// ---------------------------------------------------------------------------
// Kernel D: pf = relu(LN(feats @ W.T + b)). 992 blocks x 128 threads,
// 8 rows per block (weight reuse).
// ---------------------------------------------------------------------------
__global__ __launch_bounds__(128) void proj_kernel(
        const float* __restrict__ feats, const float* __restrict__ proj_w,
        const float* __restrict__ proj_b, const float* __restrict__ lng,
        const float* __restrict__ lnb, float* __restrict__ pf)
{
    __shared__ float fs[8*FDIM];
    __shared__ float scr[4];
    const int tid = threadIdx.x;
    const int row0 = blockIdx.x * 8;

    for (int i = tid; i < 8*FDIM; i += 128)
        fs[i] = feats[(size_t)row0*FDIM + i];
    __syncthreads();

    float acc[8];
    const float bias = proj_b[tid];
    #pragma unroll
    for (int g = 0; g < 8; ++g) acc[g] = bias;

    const float4* wrow = (const float4*)(proj_w + (size_t)tid*FDIM);
    for (int kc = 0; kc < 63; ++kc){
        float4 wA = wrow[2*kc], wB = wrow[2*kc+1];
        #pragma unroll
        for (int g = 0; g < 8; ++g){
            const float4* fp = (const float4*)(fs + g*FDIM + kc*8);
            float4 p = fp[0], q = fp[1];
            float s = acc[g];
            s = fmaf(p.x,wA.x,s); s = fmaf(p.y,wA.y,s); s = fmaf(p.z,wA.z,s); s = fmaf(p.w,wA.w,s);
            s = fmaf(q.x,wB.x,s); s = fmaf(q.y,wB.y,s); s = fmaf(q.z,wB.z,s); s = fmaf(q.w,wB.w,s);
            acc[g] = s;
        }
    }
    const float gl = lng[tid], bl = lnb[tid];
    #pragma unroll
    for (int g = 0; g < 8; ++g){
        float s1 = acc[g], s2 = acc[g]*acc[g];
        bred2(s1, s2, scr, tid);
        float m = s1 * (1.f/128.f);
        float var = fmaxf(s2 * (1.f/128.f) - m*m, 0.f);
        float y = (acc[g] - m) / sqrtf(var + 1e-5f);
        y = y*gl + bl;
        pf[(size_t)(row0 + g)*DM + tid] = fmaxf(y, 0.f);
    }
}

// ---------------------------------------------------------------------------
// Kernel F: token pooling + 3-layer transformer. 128 blocks x 128 threads.
// ---------------------------------------------------------------------------
__global__ __launch_bounds__(128) void former_kernel(
        const float* __restrict__ pf, const int* __restrict__ assign,
        const float* __restrict__ pos_enc,
        const float* __restrict__ Wqkv, const float* __restrict__ bqkv,
        const float* __restrict__ Wo,   const float* __restrict__ bo,
        const float* __restrict__ W1,   const float* __restrict__ b1,
        const float* __restrict__ W2,   const float* __restrict__ b2,
        const float* __restrict__ ln1g, const float* __restrict__ ln1b,
        const float* __restrict__ ln2g, const float* __restrict__ ln2b,
        float* __restrict__ out)
{
    __shared__ float h[5*128];
    __shared__ float qkvL[5*384];
    __shared__ float attL[100];
    __shared__ float oL[5*128];
    __shared__ float hidL[5*256];
    __shared__ int   asg[62];
    __shared__ float scr[4];

    const int b = blockIdx.x;
    const int d = threadIdx.x;

    if (d < 62) asg[d] = assign[d];
    __syncthreads();

    // token pooling
    {
        float a0=0,a1=0,a2=0,a3=0,a4=0;
        const float* pfb = pf + (size_t)b*62*DM + d;
        for (int c = 0; c < 62; ++c){
            float v = pfb[(size_t)c*DM];
            int a = asg[c];
            a0 += (a==0)?v:0.f; a1 += (a==1)?v:0.f; a2 += (a==2)?v:0.f;
            a3 += (a==3)?v:0.f; a4 += (a==4)?v:0.f;
        }
        h[0*128+d] = a0/13.f + pos_enc[0*128+d];
        h[1*128+d] = a1/13.f + pos_enc[1*128+d];
        h[2*128+d] = a2/12.f + pos_enc[2*128+d];
        h[3*128+d] = a3/12.f + pos_enc[3*128+d];
        h[4*128+d] = a4/12.f + pos_enc[4*128+d];
    }
    __syncthreads();

    for (int L = 0; L < 3; ++L){
        // ---- qkv ----
        const float* Wq = Wqkv + (size_t)L*384*128;
        float acc[3][5];
        #pragma unroll
        for (int rr = 0; rr < 3; ++rr){
            float bb = bqkv[L*384 + rr*128 + d];
            #pragma unroll
            for (int t = 0; t < 5; ++t) acc[rr][t] = bb;
        }
        for (int kc = 0; kc < 16; ++kc){
            float hr[5][8];
            #pragma unroll
            for (int t = 0; t < 5; ++t){
                float4 p = *(const float4*)&h[t*128 + kc*8];
                float4 q = *(const float4*)&h[t*128 + kc*8 + 4];
                hr[t][0]=p.x; hr[t][1]=p.y; hr[t][2]=p.z; hr[t][3]=p.w;
                hr[t][4]=q.x; hr[t][5]=q.y; hr[t][6]=q.z; hr[t][7]=q.w;
            }
            #pragma unroll
            for (int rr = 0; rr < 3; ++rr){
                float4 wA = *(const float4*)(Wq + ((size_t)(rr*128 + d))*128 + kc*8);
                float4 wB = *(const float4*)(Wq + ((size_t)(rr*128 + d))*128 + kc*8 + 4);
                #pragma unroll
                for (int t = 0; t < 5; ++t){
                    float s = acc[rr][t];
                    s=fmaf(hr[t][0],wA.x,s); s=fmaf(hr[t][1],wA.y,s);
                    s=fmaf(hr[t][2],wA.z,s); s=fmaf(hr[t][3],wA.w,s);
                    s=fmaf(hr[t][4],wB.x,s); s=fmaf(hr[t][5],wB.y,s);
                    s=fmaf(hr[t][6],wB.z,s); s=fmaf(hr[t][7],wB.w,s);
                    acc[rr][t] = s;
                }
            }
        }
        #pragma unroll
        for (int rr = 0; rr < 3; ++rr)
            #pragma unroll
            for (int t = 0; t < 5; ++t)
                qkvL[t*384 + rr*128 + d] = acc[rr][t];
        __syncthreads();

        // ---- scores ----
        if (d < 100){
            int hh = d/25, rem = d - hh*25, tq = rem/5, tk = rem - (rem/5)*5;
            const float* qq = &qkvL[tq*384 + hh*32];
            const float* kk = &qkvL[tk*384 + 128 + hh*32];
            float s = 0.f;
            #pragma unroll
            for (int j = 0; j < 32; ++j) s = fmaf(qq[j], kk[j], s);
            attL[d] = s * 0.17677669529663687f;   // 1/sqrt(32)
        }
        __syncthreads();
        if (d < 20){
            int hh = d/5, tq = d - hh*5;
            float* row = &attL[hh*25 + tq*5];
            float mx = row[0];
            #pragma unroll
            for (int j = 1; j < 5; ++j) mx = fmaxf(mx, row[j]);
            float sm = 0.f;
            #pragma unroll
            for (int j = 0; j < 5; ++j){ float e = expf(row[j]-mx); row[j] = e; sm += e; }
            float inv = 1.f/sm;
            #pragma unroll
            for (int j = 0; j < 5; ++j) row[j] *= inv;
        }
        __syncthreads();

        // ---- attention output ----
        {
            int hh = d >> 5;
            #pragma unroll
            for (int t = 0; t < 5; ++t){
                float s = 0.f;
                #pragma unroll
                for (int tk = 0; tk < 5; ++tk)
                    s = fmaf(attL[hh*25 + t*5 + tk], qkvL[tk*384 + 256 + d], s);
                oL[t*128 + d] = s;
            }
        }
        __syncthreads();

        // ---- out proj + residual + LN1 ----
        float val[5];
        {
            float bv = bo[L*128 + d];
            #pragma unroll
            for (int t = 0; t < 5; ++t) val[t] = bv;
            const float* WoR = Wo + ((size_t)L*128 + d)*128;
            for (int kc = 0; kc < 16; ++kc){
                float orr[5][8];
                #pragma unroll
                for (int t = 0; t < 5; ++t){
                    float4 p = *(const float4*)&oL[t*128 + kc*8];
                    float4 q = *(const float4*)&oL[t*128 + kc*8 + 4];
                    orr[t][0]=p.x; orr[t][1]=p.y; orr[t][2]=p.z; orr[t][3]=p.w;
                    orr[t][4]=q.x; orr[t][5]=q.y; orr[t][6]=q.z; orr[t][7]=q.w;
                }
                float4 wA = *(const float4*)(WoR + kc*8);
                float4 wB = *(const float4*)(WoR + kc*8 + 4);
                #pragma unroll
                for (int t = 0; t < 5; ++t){
                    float s = val[t];
                    s=fmaf(orr[t][0],wA.x,s); s=fmaf(orr[t][1],wA.y,s);
                    s=fmaf(orr[t][2],wA.z,s); s=fmaf(orr[t][3],wA.w,s);
                    s=fmaf(orr[t][4],wB.x,s); s=fmaf(orr[t][5],wB.y,s);
                    s=fmaf(orr[t][6],wB.z,s); s=fmaf(orr[t][7],wB.w,s);
                    val[t] = s;
                }
            }
            #pragma unroll
            for (int t = 0; t < 5; ++t) val[t] += h[t*128 + d];
        }
        {
            float ng = ln1g[L*128 + d], nb = ln1b[L*128 + d];
            #pragma unroll
            for (int t = 0; t < 5; ++t){
                float s1 = val[t], s2 = val[t]*val[t];
                bred2(s1, s2, scr, d);
                float m = s1*(1.f/128.f);
                float var = fmaxf(s2*(1.f/128.f) - m*m, 0.f);
                float y = (val[t] - m) / sqrtf(var + 1e-5f);
                h[t*128 + d] = y*ng + nb;
            }
        }
        __syncthreads();

        // ---- FF1 ----
        {
            float f1[2][5];
            #pragma unroll
            for (int rr = 0; rr < 2; ++rr){
                float bb = b1[L*256 + rr*128 + d];
                #pragma unroll
                for (int t = 0; t < 5; ++t) f1[rr][t] = bb;
            }
            const float* W1b = W1 + (size_t)L*256*128;
            for (int kc = 0; kc < 16; ++kc){
                float hr[5][8];
                #pragma unroll
                for (int t = 0; t < 5; ++t){
                    float4 p = *(const float4*)&h[t*128 + kc*8];
                    float4 q = *(const float4*)&h[t*128 + kc*8 + 4];
                    hr[t][0]=p.x; hr[t][1]=p.y; hr[t][2]=p.z; hr[t][3]=p.w;
                    hr[t][4]=q.x; hr[t][5]=q.y; hr[t][6]=q.z; hr[t][7]=q.w;
                }
                #pragma unroll
                for (int rr = 0; rr < 2; ++rr){
                    float4 wA = *(const float4*)(W1b + ((size_t)(rr*128 + d))*128 + kc*8);
                    float4 wB = *(const float4*)(W1b + ((size_t)(rr*128 + d))*128 + kc*8 + 4);
                    #pragma unroll
                    for (int t = 0; t < 5; ++t){
                        float s = f1[rr][t];
                        s=fmaf(hr[t][0],wA.x,s); s=fmaf(hr[t][1],wA.y,s);
                        s=fmaf(hr[t][2],wA.z,s); s=fmaf(hr[t][3],wA.w,s);
                        s=fmaf(hr[t][4],wB.x,s); s=fmaf(hr[t][5],wB.y,s);
                        s=fmaf(hr[t][6],wB.z,s); s=fmaf(hr[t][7],wB.w,s);
                        f1[rr][t] = s;
                    }
                }
            }
            #pragma unroll
            for (int rr = 0; rr < 2; ++rr)
                #pragma unroll
                for (int t = 0; t < 5; ++t)
                    hidL[t*256 + rr*128 + d] = fmaxf(f1[rr][t], 0.f);
        }
        __syncthreads();

        // ---- FF2 + residual + LN2 ----
        {
            float v2[5];
            float bv = b2[L*128 + d];
            #pragma unroll
            for (int t = 0; t < 5; ++t) v2[t] = bv;
            const float* W2R = W2 + ((size_t)L*128 + d)*256;
            for (int kc = 0; kc < 32; ++kc){
                float hr[5][8];
                #pragma unroll
                for (int t = 0; t < 5; ++t){
                    float4 p = *(const float4*)&hidL[t*256 + kc*8];
                    float4 q = *(const float4*)&hidL[t*256 + kc*8 + 4];
                    hr[t][0]=p.x; hr[t][1]=p.y; hr[t][2]=p.z; hr[t][3]=p.w;
                    hr[t][4]=q.x; hr[t][5]=q.y; hr[t][6]=q.z; hr[t][7]=q.w;
                }
                float4 wA = *(const float4*)(W2R + kc*8);
                float4 wB = *(const float4*)(W2R + kc*8 + 4);
                #pragma unroll
                for (int t = 0; t < 5; ++t){
                    float s = v2[t];
                    s=fmaf(hr[t][0],wA.x,s); s=fmaf(hr[t][1],wA.y,s);
                    s=fmaf(hr[t][2],wA.z,s); s=fmaf(hr[t][3],wA.w,s);
                    s=fmaf(hr[t][4],wB.x,s); s=fmaf(hr[t][5],wB.y,s);
                    s=fmaf(hr[t][6],wB.z,s); s=fmaf(hr[t][7],wB.w,s);
                    v2[t] = s;
                }
            }
            #pragma unroll
            for (int t = 0; t < 5; ++t) v2[t] += h[t*128 + d];
            float ng = ln2g[L*128 + d], nb = ln2b[L*128 + d];
            #pragma unroll
            for (int t = 0; t < 5; ++t){
                float s1 = v2[t], s2 = v2[t]*v2[t];
                bred2(s1, s2, scr, d);
                float m = s1*(1.f/128.f);
                float var = fmaxf(s2*(1.f/128.f) - m*m, 0.f);
                float y = (v2[t] - m) / sqrtf(var + 1e-5f);
                h[t*128 + d] = y*ng + nb;
            }
        }
        __syncthreads();
    }

    #pragma unroll
    for (int t = 0; t < 5; ++t)
        out[((size_t)b*5 + t)*128 + d] = h[t*128 + d];
}

// ---------------------------------------------------------------------------
extern "C" void kernel_launch(void* const* d_in, const int* in_sizes, int n_in,
                              void* d_out, int out_size, void* d_ws, size_t ws_size,
                              hipStream_t stream)
{
    const float* x        = (const float*)d_in[0];
    const float* pos_emb  = (const float*)d_in[1];
    const float* proj_w   = (const float*)d_in[2];
    const float* proj_b   = (const float*)d_in[3];
    const float* proj_lng = (const float*)d_in[4];
    const float* proj_lnb = (const float*)d_in[5];
    const float* pos_enc  = (const float*)d_in[6];
    const float* Wqkv     = (const float*)d_in[7];
    const float* bqkv     = (const float*)d_in[8];
    const float* Wo       = (const float*)d_in[9];
    const float* bo       = (const float*)d_in[10];
    const float* W1       = (const float*)d_in[11];
    const float* b1       = (const float*)d_in[12];
    const float* W2       = (const float*)d_in[13];
    const float* b2       = (const float*)d_in[14];
    const float* ln1g     = (const float*)d_in[15];
    const float* ln1b     = (const float*)d_in[16];
    const float* ln2g     = (const float*)d_in[17];
    const float* ln2b     = (const float*)d_in[18];

    float* ws    = (float*)d_ws;
    float* feats = ws;                              // 128*62*504
    float* pf    = feats + (size_t)N_SIG*FDIM;      // 128*62*128
    float* Dpart = pf;                              // 256*3844 (used before proj)
    float* gsums = pf + (size_t)N_SIG*DM;           // 15
    float* gcnt  = gsums + 15;                      // 5
    int*   assign = (int*)(gcnt + 5);               // 62
    float* basis = (float*)(assign + 64);           // 45*504

    float* out = (float*)d_out;

    basis_kernel<<<45, 256, 0, stream>>>(basis);
    feat_kernel<<<1134, 256, 0, stream>>>(x, basis, feats, gsums, gcnt);
    dist2_kernel<<<256, 256, 0, stream>>>(feats, Dpart);
    fps_kernel<<<128, 256, 0, stream>>>(Dpart, pos_emb, gsums, gcnt);
    finalize_kernel<<<1, 64, 0, stream>>>(pos_emb, gsums, gcnt, assign);
    proj_kernel<<<992, 128, 0, stream>>>(feats, proj_w, proj_b, proj_lng, proj_lnb, pf);
    former_kernel<<<128, 128, 0, stream>>>(pf, assign, pos_enc,
        Wqkv, bqkv, Wo, bo, W1, b1, W2, b2, ln1g, ln1b, ln2g, ln2b, out);
}

// Round 6
// 1060.318 us; speedup vs baseline: 1.2415x; 1.2415x over previous
//
#include <hip/hip_runtime.h>
#include <hip/hip_bf16.h>

// ===========================================================================
// EEGRCformer forward on MI355X. ALL tensors float32.
// R6: feat = transpose(x)->pair-major + lanes-over-signals DFT: x coalesced
// vmcnt loads, basis wave-uniform (scalarized, lgkm), NO LDS in kernel ->
// ~20 waves/CU. Weights pre-transposed for coalesced per-k loads in
// proj/former. dist2+fps merged back (R2 cluster).
// ===========================================================================

#define N_SIG   7936
#define FDIM    504
#define DM      128
#define CHUNK   3968          // signals per transpose/feat chunk
#define X2STR   (CHUNK*2)     // float stride of one pair-row (7936 floats)

// ws offsets (floats)
#define OFF_X2     0                      // 7,936,000 (feats aliases 0..4M)
#define OFF_PSD    7936000                // 1,999,872 (pf/Dm alias)
#define OFF_BASIS  9935872                // 22,000
#define OFF_PROJT  9957872                // 64,512
#define OFF_WQKVT  10022384               // 147,456
#define OFF_WOT    10169840               // 49,152
#define OFF_W1T    10218992               // 98,304
#define OFF_W2T    10317296               // 98,304
#define OFF_GSUM   10415600               // 15
#define OFF_GCNT   10415615               // 5
#define OFF_ASSIGN 10415620               // 64 ints

// block reduce of (a,b) over 128 threads (2 waves); scr must be >=4 floats
static __device__ __forceinline__ void bred2(float& a, float& b, volatile float* scr, int tid){
    #pragma unroll
    for (int off = 32; off > 0; off >>= 1){
        a += __shfl_down(a, off, 64);
        b += __shfl_down(b, off, 64);
    }
    if ((tid & 63) == 0){ scr[tid>>6] = a; scr[2 + (tid>>6)] = b; }
    __syncthreads();
    a = scr[0] + scr[1];
    b = scr[2] + scr[3];
    __syncthreads();
}

// ---------------------------------------------------------------------------
// Kernel P: precompute basis [cc][step][bin][4]={cosE,cosO,sinE,sinO},
// transpose all weight matrices, zero gsums/gcnt. 1875 x 256.
// ---------------------------------------------------------------------------
__global__ __launch_bounds__(256) void prep_kernel(
        const float* __restrict__ proj_w, const float* __restrict__ Wqkv,
        const float* __restrict__ Wo, const float* __restrict__ W1,
        const float* __restrict__ W2, float* __restrict__ ws)
{
    int idx = blockIdx.x*256 + threadIdx.x;
    if (idx < 22000){
        int cc = idx / 5500, r = idx % 5500;
        int step = r / 44, q = r % 44;
        int bin = q >> 2, c = q & 3;
        int k = 1 + cc*11 + bin;
        int n = 2*step + (c & 1);
        const float TPO = 0.025132741228718345f;  // 2*pi/250
        int m = (k*n) % 250;
        float th = (float)m * TPO;
        float hw = 0.5f*(1.f - cosf((float)n * TPO));
        float v = (c < 2) ? hw*cosf(th) : hw*sinf(th);
        ws[OFF_BASIS + idx] = v;
        return;
    }
    idx -= 22000;
    if (idx < 64512){                         // projT[k][d] = proj_w[d][k]
        int k = idx / 128, d = idx % 128;
        ws[OFF_PROJT + idx] = proj_w[d*504 + k];
        return;
    }
    idx -= 64512;
    if (idx < 147456){                        // WqkvT[L][k][r]
        int L = idx / 49152, rem = idx % 49152;
        int k = rem / 384, r = rem % 384;
        ws[OFF_WQKVT + idx] = Wqkv[((size_t)L*384 + r)*128 + k];
        return;
    }
    idx -= 147456;
    if (idx < 49152){                         // WoT[L][k][d]
        int L = idx / 16384, rem = idx % 16384;
        int k = rem / 128, d = rem % 128;
        ws[OFF_WOT + idx] = Wo[((size_t)L*128 + d)*128 + k];
        return;
    }
    idx -= 49152;
    if (idx < 98304){                         // W1T[L][k][r]
        int L = idx / 32768, rem = idx % 32768;
        int k = rem / 256, r = rem % 256;
        ws[OFF_W1T + idx] = W1[((size_t)L*256 + r)*128 + k];
        return;
    }
    idx -= 98304;
    if (idx < 98304){                         // W2T[L][k(256)][d]
        int L = idx / 32768, rem = idx % 32768;
        int k = rem / 128, d = rem % 128;
        ws[OFF_W2T + idx] = W2[((size_t)L*128 + d)*256 + k];
        return;
    }
    idx -= 98304;
    if (idx < 20) ws[OFF_GSUM + idx] = 0.f;   // gsums(15)+gcnt(5)
}

// ---------------------------------------------------------------------------
// Kernel T: transpose one chunk of x -> x2[pair][sig*2]. grid (62,40) x 256.
// ---------------------------------------------------------------------------
__global__ __launch_bounds__(256) void transpose_kernel(
        const float* __restrict__ x, float* __restrict__ x2c, int sigBase)
{
    __shared__ float xs[64*53];
    const int tid  = threadIdx.x;
    const int sig0 = blockIdx.x * 64;     // local within chunk
    const int n0   = blockIdx.y * 50;

    for (int idx = tid; idx < 3200; idx += 256){
        int r = idx / 50, c = idx - r*50;
        xs[r*53 + c] = x[(size_t)(sigBase + sig0 + r)*2000 + n0 + c];
    }
    __syncthreads();
    for (int idx = tid; idx < 1600; idx += 256){
        int c2 = idx >> 6, lane = idx & 63;
        float2 v = make_float2(xs[lane*53 + 2*c2], xs[lane*53 + 2*c2 + 1]);
        *(float2*)(x2c + (size_t)(n0/2 + c2)*X2STR + (sig0 + lane)*2) = v;
    }
}

// ---------------------------------------------------------------------------
// Kernel A: DFT -> band psd means -> global psd scratch. grid (62,9) x 256.
// wave = one window of 64 signals; lanes = signals (coalesced x), basis
// wave-uniform (scalar). No LDS.
// ---------------------------------------------------------------------------
__global__ __launch_bounds__(256) void feat_kernel(
        const float* __restrict__ x2c, const float* __restrict__ basisP,
        float* __restrict__ psd, int sigBase)
{
    constexpr int band_of[46] = {
        -1, 0,0,0, 1,1,1,1, 2,2,2,2, 3,3,3,3, 4,4,4,4,
        5,5,5,5,5,5,5,5,5,5,
        6,6,6,6,6,6,6,6,6,6,6,6,6,6,6};
    constexpr float invcnt[7] = {1.f/3.f, 0.25f, 0.25f, 0.25f, 0.25f, 0.1f, 1.f/15.f};

    const int tid  = threadIdx.x;
    const int wave = tid >> 6, lane = tid & 63;
    const int win  = blockIdx.y * 4 + wave;
    const int ls   = blockIdx.x * 64 + lane;      // local sig in chunk
    const int gsig = sigBase + ls;

    float bands[7] = {0,0,0,0,0,0,0};

    const float2* xbase = (const float2*)x2c + (size_t)(25*win)*CHUNK + ls;

    #pragma unroll
    for (int cc = 0; cc < 4; ++cc){
        const float* bp = basisP + cc*5500;
        float ar[11], ai[11];
        #pragma unroll
        for (int k = 0; k < 11; ++k){ ar[k] = 0.f; ai[k] = 0.f; }

        const float2* xp = xbase;
        for (int step = 0; step < 125; ++step){
            float2 xv = *xp; xp += CHUNK;
            const float* bs = bp + step*44;
            #pragma unroll
            for (int k = 0; k < 11; ++k){
                float4 b = *(const float4*)(bs + k*4);
                ar[k] = fmaf(xv.x, b.x, fmaf(xv.y, b.y, ar[k]));
                ai[k] = fmaf(xv.x, b.z, fmaf(xv.y, b.w, ai[k]));
            }
        }
        #pragma unroll
        for (int k = 0; k < 11; ++k){
            float p = fmaf(ar[k], ar[k], ai[k]*ai[k]) * (1.0f/250.0f);
            bands[band_of[1 + cc*11 + k]] += p;
        }
    }
    float* ob = psd + (size_t)gsig*252 + win*7;
    #pragma unroll
    for (int b = 0; b < 7; ++b) ob[b] = bands[b] * invcnt[b];
}

// ---------------------------------------------------------------------------
// Kernel N: per-signal z-norm of psd + DE -> feats. 1984 x 256 (wave=sig).
// ---------------------------------------------------------------------------
__global__ __launch_bounds__(256) void norm_kernel(
        const float* __restrict__ psd, float* __restrict__ feats)
{
    const int tid = threadIdx.x;
    const int wave = tid >> 6, lane = tid & 63;
    const int sig = blockIdx.x*4 + wave;

    float pv[4], dv[4];
    float s1p=0,s2p=0,s1d=0,s2d=0;
    #pragma unroll
    for (int i = 0; i < 4; ++i){
        int e = lane + i*64;
        if (e < 252){
            float p = psd[(size_t)sig*252 + e];
            float d = 0.5f * logf(17.079468445347134f*p + 1e-9f);
            pv[i] = p; dv[i] = d;
            s1p += p; s2p += p*p; s1d += d; s2d += d*d;
        }
    }
    #pragma unroll
    for (int off = 32; off > 0; off >>= 1){
        s1p += __shfl_down(s1p, off, 64); s2p += __shfl_down(s2p, off, 64);
        s1d += __shfl_down(s1d, off, 64); s2d += __shfl_down(s2d, off, 64);
    }
    s1p = __shfl(s1p, 0, 64); s2p = __shfl(s2p, 0, 64);
    s1d = __shfl(s1d, 0, 64); s2d = __shfl(s2d, 0, 64);
    float mp = s1p / 252.f;
    float sp = sqrtf(fmaxf((s2p - 252.f*mp*mp) / 251.f, 0.f)) + 1e-9f;
    float md = s1d / 252.f;
    float sd = sqrtf(fmaxf((s2d - 252.f*md*md) / 251.f, 0.f)) + 1e-9f;

    float* ob = feats + (size_t)sig * FDIM;
    #pragma unroll
    for (int i = 0; i < 4; ++i){
        int e = lane + i*64;
        if (e < 252){
            int w = e / 7, bi = e - w*7;
            ob[w*14 + bi]     = (pv[i] - mp) / sp;
            ob[w*14 + 7 + bi] = (dv[i] - md) / sd;
        }
    }
}

// ---------------------------------------------------------------------------
// Kernel B: per-batch 62x62 feature distances -> FPS(5) -> temp assign ->
// atomic pos sums/counts. 128 blocks x 256 threads. (R2 structure)
// ---------------------------------------------------------------------------
__global__ __launch_bounds__(256) void cluster_kernel(
        const float* __restrict__ feats, const float* __restrict__ pos_emb,
        float* __restrict__ gsums, float* __restrict__ gcnt)
{
    __shared__ float Fc[62*130];
    __shared__ float Dm[62*62];
    __shared__ float mdv[62];
    __shared__ float rsv[62];
    __shared__ int   seli[5];
    __shared__ float ccen[5][3];

    const int tid = threadIdx.x;
    const int b   = blockIdx.x;

    for (int i = tid; i < 3844; i += 256) Dm[i] = 0.f;
    __syncthreads();

    for (int ch = 0; ch < 4; ++ch){
        for (int i = tid; i < 62*126; i += 256){
            int r = i / 126, dc = i - r*126;
            Fc[r*130 + dc] = feats[((size_t)b*62 + r)*FDIM + ch*126 + dc];
        }
        __syncthreads();
        for (int e = tid; e < 3844; e += 256){
            int i = e / 62, j = e - i*62;
            const float2* ri = (const float2*)(Fc + i*130);
            const float2* rj = (const float2*)(Fc + j*130);
            float acc = 0.f;
            for (int t = 0; t < 63; ++t){
                float2 a = ri[t], c = rj[t];
                float d0 = a.x - c.x, d1 = a.y - c.y;
                acc = fmaf(d0, d0, acc); acc = fmaf(d1, d1, acc);
            }
            Dm[e] += acc;
        }
        __syncthreads();
    }
    for (int e = tid; e < 3844; e += 256) Dm[e] = sqrtf(Dm[e]);
    __syncthreads();

    if (tid < 62){ float s = 0.f; for (int j = 0; j < 62; ++j) s += Dm[tid*62 + j]; rsv[tid] = s; }
    __syncthreads();
    if (tid == 0){
        int bi = 0; float bv = rsv[0];
        for (int i = 1; i < 62; ++i) if (rsv[i] > bv){ bv = rsv[i]; bi = i; }
        seli[0] = bi;
    }
    __syncthreads();
    if (tid < 62) mdv[tid] = Dm[seli[0]*62 + tid];
    __syncthreads();
    for (int it = 1; it < 5; ++it){
        if (tid == 0){
            int bi = 0; float bv = mdv[0];
            for (int i = 1; i < 62; ++i) if (mdv[i] > bv){ bv = mdv[i]; bi = i; }
            seli[it] = bi;
        }
        __syncthreads();
        if (tid < 62) mdv[tid] = fminf(mdv[tid], Dm[seli[it]*62 + tid]);
        __syncthreads();
    }
    if (tid < 5){
        int c0 = seli[tid];
        #pragma unroll
        for (int j = 0; j < 3; ++j) ccen[tid][j] = pos_emb[((size_t)b*62 + c0)*3 + j];
    }
    __syncthreads();
    if (tid < 62){
        float px = pos_emb[((size_t)b*62 + tid)*3 + 0];
        float py = pos_emb[((size_t)b*62 + tid)*3 + 1];
        float pz = pos_emb[((size_t)b*62 + tid)*3 + 2];
        int best = 0; float bd = 3.4e38f;
        #pragma unroll
        for (int t = 0; t < 5; ++t){
            float dx = px - ccen[t][0], dy = py - ccen[t][1], dz = pz - ccen[t][2];
            float d2 = dx*dx + dy*dy + dz*dz;
            if (d2 < bd){ bd = d2; best = t; }
        }
        atomicAdd(&gsums[best*3 + 0], px);
        atomicAdd(&gsums[best*3 + 1], py);
        atomicAdd(&gsums[best*3 + 2], pz);
        atomicAdd(&gcnt[best], 1.f);
    }
}

// ---------------------------------------------------------------------------
// Kernel C: pos FPS centers, center update, stable order + greedy assignment.
// ---------------------------------------------------------------------------
__global__ __launch_bounds__(64) void finalize_kernel(
        const float* __restrict__ pos_emb, const float* __restrict__ gsums,
        const float* __restrict__ gcnt, int* __restrict__ assign_out)
{
    __shared__ float P[62*3];
    __shared__ float Dp[62*62];
    __shared__ float rsv[62];
    __shared__ float mdv[62];
    __shared__ int   seli[5];
    __shared__ float cenS[5][3];
    __shared__ int   ordS[62][5];
    const int tid = threadIdx.x;

    if (tid < 62){
        #pragma unroll
        for (int j = 0; j < 3; ++j) P[tid*3 + j] = pos_emb[(size_t)tid*3 + j];
    }
    __syncthreads();
    if (tid < 62){
        float xi = P[tid*3], yi = P[tid*3+1], zi = P[tid*3+2];
        float s = 0.f;
        for (int j = 0; j < 62; ++j){
            float dx = xi - P[j*3], dy = yi - P[j*3+1], dz = zi - P[j*3+2];
            float d = sqrtf(dx*dx + dy*dy + dz*dz);
            Dp[tid*62 + j] = d; s += d;
        }
        rsv[tid] = s;
    }
    __syncthreads();
    if (tid == 0){
        int bi = 0; float bv = rsv[0];
        for (int i = 1; i < 62; ++i) if (rsv[i] > bv){ bv = rsv[i]; bi = i; }
        seli[0] = bi;
        for (int i = 0; i < 62; ++i) mdv[i] = Dp[bi*62 + i];
        for (int it = 1; it < 5; ++it){
            int fi = 0; float fv = mdv[0];
            for (int i = 1; i < 62; ++i) if (mdv[i] > fv){ fv = mdv[i]; fi = i; }
            seli[it] = fi;
            for (int i = 0; i < 62; ++i) mdv[i] = fminf(mdv[i], Dp[fi*62 + i]);
        }
        float cen[5][3], avg[5][3];
        for (int t = 0; t < 5; ++t)
            for (int j = 0; j < 3; ++j) cen[t][j] = P[seli[t]*3 + j];
        for (int t = 0; t < 5; ++t){
            float c = gcnt[t];
            for (int j = 0; j < 3; ++j)
                avg[t][j] = (c > 0.f) ? gsums[t*3 + j] / fmaxf(c, 1.f) : 0.f;
        }
        for (int i = 0; i < 5; ++i){
            int m = 0; float bv2 = 3.4e38f;
            for (int j = 0; j < 5; ++j){
                float dx = cen[i][0]-avg[j][0], dy = cen[i][1]-avg[j][1], dz = cen[i][2]-avg[j][2];
                float d2 = dx*dx + dy*dy + dz*dz;
                if (d2 < bv2){ bv2 = d2; m = j; }
            }
            for (int j = 0; j < 3; ++j) cenS[i][j] = 0.8f*cen[i][j] + 0.2f*avg[m][j];
        }
    }
    __syncthreads();
    if (tid < 62){
        float dd[5];
        #pragma unroll
        for (int t = 0; t < 5; ++t){
            float dx = P[tid*3]-cenS[t][0], dy = P[tid*3+1]-cenS[t][1], dz = P[tid*3+2]-cenS[t][2];
            dd[t] = sqrtf(dx*dx + dy*dy + dz*dz);
        }
        bool tk[5] = {false,false,false,false,false};
        #pragma unroll
        for (int s = 0; s < 5; ++s){
            int best = -1;
            #pragma unroll
            for (int t = 0; t < 5; ++t)
                if (!tk[t] && (best < 0 || dd[t] < dd[best])) best = t;
            tk[best] = true; ordS[tid][s] = best;
        }
    }
    __syncthreads();
    if (tid == 0){
        const int sizesA[5] = {13,13,12,12,12};
        int counts[5] = {0,0,0,0,0};
        for (int i = 0; i < 62; ++i){
            int cl = ordS[i][0];
            #pragma unroll
            for (int s = 0; s < 5; ++s){
                int t = ordS[i][s];
                if (counts[t] < sizesA[t]){ cl = t; break; }
            }
            counts[cl]++;
            assign_out[i] = cl;
        }
    }
}

// ---------------------------------------------------------------------------
// Kernel D: pf = relu(LN(feats @ W.T + b)) with TRANSPOSED weights.
// 992 blocks x 128 threads, 8 rows/block.
// ---------------------------------------------------------------------------
__global__ __launch_bounds__(128) void proj_kernel(
        const float* __restrict__ feats, const float* __restrict__ projT,
        const float* __restrict__ proj_b, const float* __restrict__ lng,
        const float* __restrict__ lnb, float* __restrict__ pf)
{
    __shared__ float fs[8*FDIM];
    __shared__ float scr[4];
    const int tid = threadIdx.x;
    const int row0 = blockIdx.x * 8;

    for (int i = tid; i < 8*FDIM; i += 128)
        fs[i] = feats[(size_t)row0*FDIM + i];
    __syncthreads();

    float acc[8];
    const float bias = proj_b[tid];
    #pragma unroll
    for (int g = 0; g < 8; ++g) acc[g] = bias;

    #pragma unroll 4
    for (int k = 0; k < FDIM; ++k){
        float w = projT[k*128 + tid];          // coalesced
        #pragma unroll
        for (int g = 0; g < 8; ++g)
            acc[g] = fmaf(fs[g*FDIM + k], w, acc[g]);
    }
    const float gl = lng[tid], bl = lnb[tid];
    #pragma unroll
    for (int g = 0; g < 8; ++g){
        float s1 = acc[g], s2 = acc[g]*acc[g];
        bred2(s1, s2, scr, tid);
        float m = s1 * (1.f/128.f);
        float var = fmaxf(s2 * (1.f/128.f) - m*m, 0.f);
        float y = (acc[g] - m) / sqrtf(var + 1e-5f);
        y = y*gl + bl;
        pf[(size_t)(row0 + g)*DM + tid] = fmaxf(y, 0.f);
    }
}

// ---------------------------------------------------------------------------
// Kernel F: token pooling + 3-layer transformer, TRANSPOSED weights.
// 128 blocks x 128 threads.
// ---------------------------------------------------------------------------
__global__ __launch_bounds__(128) void former_kernel(
        const float* __restrict__ pf, const int* __restrict__ assign,
        const float* __restrict__ pos_enc,
        const float* __restrict__ WqkvT, const float* __restrict__ bqkv,
        const float* __restrict__ WoT,   const float* __restrict__ bo,
        const float* __restrict__ W1T,   const float* __restrict__ b1,
        const float* __restrict__ W2T,   const float* __restrict__ b2,
        const float* __restrict__ ln1g, const float* __restrict__ ln1b,
        const float* __restrict__ ln2g, const float* __restrict__ ln2b,
        float* __restrict__ out)
{
    __shared__ float h[5*128];
    __shared__ float qkvL[5*384];
    __shared__ float attL[100];
    __shared__ float oL[5*128];
    __shared__ float hidL[5*256];
    __shared__ int   asg[62];
    __shared__ float scr[4];

    const int b = blockIdx.x;
    const int d = threadIdx.x;

    if (d < 62) asg[d] = assign[d];
    __syncthreads();

    {   // token pooling
        float a0=0,a1=0,a2=0,a3=0,a4=0;
        const float* pfb = pf + (size_t)b*62*DM + d;
        for (int c = 0; c < 62; ++c){
            float v = pfb[(size_t)c*DM];
            int a = asg[c];
            a0 += (a==0)?v:0.f; a1 += (a==1)?v:0.f; a2 += (a==2)?v:0.f;
            a3 += (a==3)?v:0.f; a4 += (a==4)?v:0.f;
        }
        h[0*128+d] = a0/13.f + pos_enc[0*128+d];
        h[1*128+d] = a1/13.f + pos_enc[1*128+d];
        h[2*128+d] = a2/12.f + pos_enc[2*128+d];
        h[3*128+d] = a3/12.f + pos_enc[3*128+d];
        h[4*128+d] = a4/12.f + pos_enc[4*128+d];
    }
    __syncthreads();

    for (int L = 0; L < 3; ++L){
        // ---- qkv: acc[rr][t] = bias + sum_k h[t][k] * WqkvT[L][k][rr*128+d]
        float acc[3][5];
        #pragma unroll
        for (int rr = 0; rr < 3; ++rr){
            float bb = bqkv[L*384 + rr*128 + d];
            #pragma unroll
            for (int t = 0; t < 5; ++t) acc[rr][t] = bb;
        }
        {
            const float* WT = WqkvT + (size_t)L*128*384;
            #pragma unroll 4
            for (int k = 0; k < 128; ++k){
                float h0 = h[0*128+k], h1 = h[1*128+k], h2 = h[2*128+k];
                float h3 = h[3*128+k], h4 = h[4*128+k];
                #pragma unroll
                for (int rr = 0; rr < 3; ++rr){
                    float w = WT[(size_t)k*384 + rr*128 + d];
                    acc[rr][0] = fmaf(h0, w, acc[rr][0]);
                    acc[rr][1] = fmaf(h1, w, acc[rr][1]);
                    acc[rr][2] = fmaf(h2, w, acc[rr][2]);
                    acc[rr][3] = fmaf(h3, w, acc[rr][3]);
                    acc[rr][4] = fmaf(h4, w, acc[rr][4]);
                }
            }
        }
        #pragma unroll
        for (int rr = 0; rr < 3; ++rr)
            #pragma unroll
            for (int t = 0; t < 5; ++t)
                qkvL[t*384 + rr*128 + d] = acc[rr][t];
        __syncthreads();

        // ---- scores ----
        if (d < 100){
            int hh = d/25, rem = d - hh*25, tq = rem/5, tk = rem - (rem/5)*5;
            const float* qq = &qkvL[tq*384 + hh*32];
            const float* kk = &qkvL[tk*384 + 128 + hh*32];
            float s = 0.f;
            #pragma unroll
            for (int j = 0; j < 32; ++j) s = fmaf(qq[j], kk[j], s);
            attL[d] = s * 0.17677669529663687f;
        }
        __syncthreads();
        if (d < 20){
            int hh = d/5, tq = d - hh*5;
            float* row = &attL[hh*25 + tq*5];
            float mx = row[0];
            #pragma unroll
            for (int j = 1; j < 5; ++j) mx = fmaxf(mx, row[j]);
            float sm = 0.f;
            #pragma unroll
            for (int j = 0; j < 5; ++j){ float e = expf(row[j]-mx); row[j] = e; sm += e; }
            float inv = 1.f/sm;
            #pragma unroll
            for (int j = 0; j < 5; ++j) row[j] *= inv;
        }
        __syncthreads();

        // ---- attention output ----
        {
            int hh = d >> 5;
            #pragma unroll
            for (int t = 0; t < 5; ++t){
                float s = 0.f;
                #pragma unroll
                for (int tk = 0; tk < 5; ++tk)
                    s = fmaf(attL[hh*25 + t*5 + tk], qkvL[tk*384 + 256 + d], s);
                oL[t*128 + d] = s;
            }
        }
        __syncthreads();

        // ---- out proj + residual + LN1 ----
        float val[5];
        {
            float bv = bo[L*128 + d];
            #pragma unroll
            for (int t = 0; t < 5; ++t) val[t] = bv;
            const float* WT = WoT + (size_t)L*128*128;
            #pragma unroll 4
            for (int k = 0; k < 128; ++k){
                float w = WT[(size_t)k*128 + d];
                #pragma unroll
                for (int t = 0; t < 5; ++t)
                    val[t] = fmaf(oL[t*128 + k], w, val[t]);
            }
            #pragma unroll
            for (int t = 0; t < 5; ++t) val[t] += h[t*128 + d];
        }
        {
            float ng = ln1g[L*128 + d], nb = ln1b[L*128 + d];
            #pragma unroll
            for (int t = 0; t < 5; ++t){
                float s1 = val[t], s2 = val[t]*val[t];
                bred2(s1, s2, scr, d);
                float m = s1*(1.f/128.f);
                float var = fmaxf(s2*(1.f/128.f) - m*m, 0.f);
                float y = (val[t] - m) / sqrtf(var + 1e-5f);
                h[t*128 + d] = y*ng + nb;
            }
        }
        __syncthreads();

        // ---- FF1 ----
        {
            float f1[2][5];
            #pragma unroll
            for (int rr = 0; rr < 2; ++rr){
                float bb = b1[L*256 + rr*128 + d];
                #pragma unroll
                for (int t = 0; t < 5; ++t) f1[rr][t] = bb;
            }
            const float* WT = W1T + (size_t)L*128*256;
            #pragma unroll 4
            for (int k = 0; k < 128; ++k){
                float h0 = h[0*128+k], h1 = h[1*128+k], h2 = h[2*128+k];
                float h3 = h[3*128+k], h4 = h[4*128+k];
                #pragma unroll
                for (int rr = 0; rr < 2; ++rr){
                    float w = WT[(size_t)k*256 + rr*128 + d];
                    f1[rr][0] = fmaf(h0, w, f1[rr][0]);
                    f1[rr][1] = fmaf(h1, w, f1[rr][1]);
                    f1[rr][2] = fmaf(h2, w, f1[rr][2]);
                    f1[rr][3] = fmaf(h3, w, f1[rr][3]);
                    f1[rr][4] = fmaf(h4, w, f1[rr][4]);
                }
            }
            #pragma unroll
            for (int rr = 0; rr < 2; ++rr)
                #pragma unroll
                for (int t = 0; t < 5; ++t)
                    hidL[t*256 + rr*128 + d] = fmaxf(f1[rr][t], 0.f);
        }
        __syncthreads();

        // ---- FF2 + residual + LN2 ----
        {
            float v2[5];
            float bv = b2[L*128 + d];
            #pragma unroll
            for (int t = 0; t < 5; ++t) v2[t] = bv;
            const float* WT = W2T + (size_t)L*256*128;
            #pragma unroll 4
            for (int k = 0; k < 256; ++k){
                float w = WT[(size_t)k*128 + d];
                #pragma unroll
                for (int t = 0; t < 5; ++t)
                    v2[t] = fmaf(hidL[t*256 + k], w, v2[t]);
            }
            #pragma unroll
            for (int t = 0; t < 5; ++t) v2[t] += h[t*128 + d];
            float ng = ln2g[L*128 + d], nb = ln2b[L*128 + d];
            #pragma unroll
            for (int t = 0; t < 5; ++t){
                float s1 = v2[t], s2 = v2[t]*v2[t];
                bred2(s1, s2, scr, d);
                float m = s1*(1.f/128.f);
                float var = fmaxf(s2*(1.f/128.f) - m*m, 0.f);
                float y = (v2[t] - m) / sqrtf(var + 1e-5f);
                h[t*128 + d] = y*ng + nb;
            }
        }
        __syncthreads();
    }

    #pragma unroll
    for (int t = 0; t < 5; ++t)
        out[((size_t)b*5 + t)*128 + d] = h[t*128 + d];
}

// ---------------------------------------------------------------------------
extern "C" void kernel_launch(void* const* d_in, const int* in_sizes, int n_in,
                              void* d_out, int out_size, void* d_ws, size_t ws_size,
                              hipStream_t stream)
{
    const float* x        = (const float*)d_in[0];
    const float* pos_emb  = (const float*)d_in[1];
    const float* proj_w   = (const float*)d_in[2];
    const float* proj_b   = (const float*)d_in[3];
    const float* proj_lng = (const float*)d_in[4];
    const float* proj_lnb = (const float*)d_in[5];
    const float* pos_enc  = (const float*)d_in[6];
    const float* Wqkv     = (const float*)d_in[7];
    const float* bqkv     = (const float*)d_in[8];
    const float* Wo       = (const float*)d_in[9];
    const float* bo       = (const float*)d_in[10];
    const float* W1       = (const float*)d_in[11];
    const float* b1       = (const float*)d_in[12];
    const float* W2       = (const float*)d_in[13];
    const float* b2       = (const float*)d_in[14];
    const float* ln1g     = (const float*)d_in[15];
    const float* ln1b     = (const float*)d_in[16];
    const float* ln2g     = (const float*)d_in[17];
    const float* ln2b     = (const float*)d_in[18];

    float* ws    = (float*)d_ws;
    float* x2c   = ws + OFF_X2;        // chunk transpose dest (aliased by feats later)
    float* feats = ws + OFF_X2;        // 7936*504, written by norm after x2 dead
    float* psd   = ws + OFF_PSD;       // 7936*252
    float* pf    = ws + OFF_PSD;       // alias (psd dead after norm)
    float* basisP= ws + OFF_BASIS;
    float* projT = ws + OFF_PROJT;
    float* WqkvT = ws + OFF_WQKVT;
    float* WoT   = ws + OFF_WOT;
    float* W1T   = ws + OFF_W1T;
    float* W2T   = ws + OFF_W2T;
    float* gsums = ws + OFF_GSUM;
    float* gcnt  = ws + OFF_GCNT;
    int*   assign= (int*)(ws + OFF_ASSIGN);

    float* out = (float*)d_out;

    prep_kernel<<<1875, 256, 0, stream>>>(proj_w, Wqkv, Wo, W1, W2, ws);
    // chunk 0
    transpose_kernel<<<dim3(62,40), 256, 0, stream>>>(x, x2c, 0);
    feat_kernel<<<dim3(62,9), 256, 0, stream>>>(x2c, basisP, psd, 0);
    // chunk 1
    transpose_kernel<<<dim3(62,40), 256, 0, stream>>>(x, x2c, CHUNK);
    feat_kernel<<<dim3(62,9), 256, 0, stream>>>(x2c, basisP, psd, CHUNK);

    norm_kernel<<<1984, 256, 0, stream>>>(psd, feats);
    cluster_kernel<<<128, 256, 0, stream>>>(feats, pos_emb, gsums, gcnt);
    finalize_kernel<<<1, 64, 0, stream>>>(pos_emb, gsums, gcnt, assign);
    proj_kernel<<<992, 128, 0, stream>>>(feats, projT, proj_b, proj_lng, proj_lnb, pf);
    former_kernel<<<128, 128, 0, stream>>>(pf, assign, pos_enc,
        WqkvT, bqkv, WoT, bo, W1T, b1, W2T, b2, ln1g, ln1b, ln2g, ln2b, out);
}